// Round 4
// baseline (195.246 us; speedup 1.0000x reference)
//
#include <hip/hip_runtime.h>
#include <hip/hip_bf16.h>
#include <math.h>

// GAT, N=4096, NFEAT=512, NHID=64, NHEADS=8, NCLASS=41, EDGE_P=0.004.
// Adjacency ~17 nnz/row -> both attention layers are exactly sparse.
// Layer-1 GEMM uses bf16 MFMA with split-bf16 (hi+lo) 3-term products;
// x/W are pre-split once (prep) so GEMM staging is pure vector copies.
// att1+wh2 fused per-node (8 waves = 8 heads). s1/s2 fused in GEMM epilogue.

#define N 4096
#define NFEAT 512
#define NHID 64
#define NHEADS 8
#define NCLASS 41
#define ALPHA 0.2f
#define ELLW 64   // Binomial(4096,0.004): mean 16.4, P(cnt>64) ~ 1e-18

using short8  = __attribute__((ext_vector_type(8))) short;
using floatx4 = __attribute__((ext_vector_type(4))) float;

__device__ __forceinline__ float wred_max(float v) {
#pragma unroll
  for (int o = 32; o; o >>= 1) v = fmaxf(v, __shfl_xor(v, o, 64));
  return v;
}
__device__ __forceinline__ float wred_sum(float v) {
#pragma unroll
  for (int o = 32; o; o >>= 1) v += __shfl_xor(v, o, 64);
  return v;
}

__device__ __forceinline__ void split_bf16(float v, short& hi, short& lo) {
  __hip_bfloat16 hb = __float2bfloat16(v);
  float hf = __bfloat162float(hb);
  __hip_bfloat16 lb = __float2bfloat16(v - hf);
  hi = *reinterpret_cast<short*>(&hb);
  lo = *reinterpret_cast<short*>(&lb);
}

// ---------------------------------------------------------------- build ELL
__global__ __launch_bounds__(256) void build_ell(const float* __restrict__ adj,
                                                 int* __restrict__ cols,
                                                 int* __restrict__ cnts) {
  __shared__ int c;
  const int row = blockIdx.x;
  if (threadIdx.x == 0) c = 0;
  __syncthreads();
  const float4* arow = (const float4*)(adj + (size_t)row * N);
  for (int j4 = threadIdx.x; j4 < N / 4; j4 += 256) {
    float4 v = arow[j4];
    if (v.x > 0.f) { int p = atomicAdd(&c, 1); if (p < ELLW) cols[row * ELLW + p] = j4 * 4 + 0; }
    if (v.y > 0.f) { int p = atomicAdd(&c, 1); if (p < ELLW) cols[row * ELLW + p] = j4 * 4 + 1; }
    if (v.z > 0.f) { int p = atomicAdd(&c, 1); if (p < ELLW) cols[row * ELLW + p] = j4 * 4 + 2; }
    if (v.w > 0.f) { int p = atomicAdd(&c, 1); if (p < ELLW) cols[row * ELLW + p] = j4 * 4 + 3; }
  }
  __syncthreads();
  if (threadIdx.x == 0) cnts[row] = min(c, ELLW);
}

// --------------- prep: split x -> bf16 hi/lo; split+transpose W_heads hi/lo
// blocks [0,2048): x (float4 per thread). blocks [2048,3072): W transpose.
__global__ __launch_bounds__(256) void prep(const float* __restrict__ x,
                                            const float* __restrict__ W,
                                            short* __restrict__ Xhi,
                                            short* __restrict__ Xlo,
                                            short* __restrict__ Wthi,
                                            short* __restrict__ Wtlo) {
  if (blockIdx.x < 2048) {
    const int t = blockIdx.x * 256 + threadIdx.x;      // float4 index
    const float4 v = ((const float4*)x)[t];
    short h0, l0, h1, l1, h2, l2, h3, l3;
    split_bf16(v.x, h0, l0);
    split_bf16(v.y, h1, l1);
    split_bf16(v.z, h2, l2);
    split_bf16(v.w, h3, l3);
    ((short4*)Xhi)[t] = make_short4(h0, h1, h2, h3);
    ((short4*)Xlo)[t] = make_short4(l0, l1, l2, l3);
  } else {
    const int t = (blockIdx.x - 2048) * 256 + threadIdx.x;  // 0..262143
    const int h = t >> 15, r = t & 32767;
    const int d = r >> 9, k = r & 511;                 // write-coalesced
    float v = W[(size_t)h * 32768 + (size_t)k * 64 + d];
    short hi, lo;
    split_bf16(v, hi, lo);
    Wthi[(size_t)h * 32768 + d * 512 + k] = hi;
    Wtlo[(size_t)h * 32768 + d * 512 + k] = lo;
  }
}

// ----------------- Wh = x @ W_heads via split-bf16 MFMA; fused s1/s2 epilogue
// grid (head fast, row-tile slow) so the 8 head-blocks of one row tile share
// the x slice through L2. Staging = pure uint4 copies of pre-split bf16.
__global__ __launch_bounds__(256) void wh_gemm_mfma(
    const short* __restrict__ Xhi, const short* __restrict__ Xlo,
    const short* __restrict__ Wthi, const short* __restrict__ Wtlo,
    const float* __restrict__ a_heads,
    float* __restrict__ Wh, float* __restrict__ s1, float* __restrict__ s2) {
  __shared__ __align__(16) short Ahi[64 * 72];
  __shared__ __align__(16) short Alo[64 * 72];
  __shared__ __align__(16) short Bhi[64 * 72];
  __shared__ __align__(16) short Blo[64 * 72];
  const int h = blockIdx.x;
  const int n0 = blockIdx.y * 64;
  const int tid = threadIdx.x;
  const int w = tid >> 6, L = tid & 63;

  floatx4 acc[4];
#pragma unroll
  for (int f = 0; f < 4; f++) acc[f] = (floatx4){0.f, 0.f, 0.f, 0.f};

  for (int k0 = 0; k0 < NFEAT; k0 += 64) {
    __syncthreads();
#pragma unroll
    for (int i = 0; i < 2; i++) {
      const int g = tid + 256 * i;       // (row, 8-elem k group)
      const int row = g >> 3, kg = (g & 7) * 8;
      const size_t asrc = (size_t)(n0 + row) * NFEAT + k0 + kg;
      *(uint4*)&Ahi[row * 72 + kg] = *(const uint4*)&Xhi[asrc];
      *(uint4*)&Alo[row * 72 + kg] = *(const uint4*)&Xlo[asrc];
      const size_t bsrc = (size_t)h * 32768 + (size_t)row * 512 + k0 + kg;
      *(uint4*)&Bhi[row * 72 + kg] = *(const uint4*)&Wthi[bsrc];
      *(uint4*)&Blo[row * 72 + kg] = *(const uint4*)&Wtlo[bsrc];
    }
    __syncthreads();
#pragma unroll
    for (int ks = 0; ks < 2; ks++) {
      const int koff = ks * 32 + (L >> 4) * 8;
      short8 ahi = *(const short8*)&Ahi[(w * 16 + (L & 15)) * 72 + koff];
      short8 alo = *(const short8*)&Alo[(w * 16 + (L & 15)) * 72 + koff];
#pragma unroll
      for (int f = 0; f < 4; f++) {
        short8 bhi = *(const short8*)&Bhi[(f * 16 + (L & 15)) * 72 + koff];
        short8 blo = *(const short8*)&Blo[(f * 16 + (L & 15)) * 72 + koff];
        acc[f] = __builtin_amdgcn_mfma_f32_16x16x32_bf16(ahi, bhi, acc[f], 0, 0, 0);
        acc[f] = __builtin_amdgcn_mfma_f32_16x16x32_bf16(ahi, blo, acc[f], 0, 0, 0);
        acc[f] = __builtin_amdgcn_mfma_f32_16x16x32_bf16(alo, bhi, acc[f], 0, 0, 0);
      }
    }
  }

  // Epilogue: write Wh (fp32) + fused s1/s2 = Wh . a1 / a2
  const int q = L >> 4, c16 = L & 15;
  float a1v[4], a2v[4];
#pragma unroll
  for (int f = 0; f < 4; f++) {
    a1v[f] = a_heads[h * 128 + f * 16 + c16];
    a2v[f] = a_heads[h * 128 + 64 + f * 16 + c16];
  }
  float p1[4] = {0.f, 0.f, 0.f, 0.f}, p2[4] = {0.f, 0.f, 0.f, 0.f};
#pragma unroll
  for (int f = 0; f < 4; f++)
#pragma unroll
    for (int r = 0; r < 4; r++) {
      const float vv = acc[f][r];
      const int row = n0 + w * 16 + q * 4 + r;
      Wh[((size_t)(h << 12) + row) * NHID + f * 16 + c16] = vv;
      p1[r] += vv * a1v[f];
      p2[r] += vv * a2v[f];
    }
#pragma unroll
  for (int r = 0; r < 4; r++)
#pragma unroll
    for (int o = 1; o < 16; o <<= 1) {
      p1[r] += __shfl_xor(p1[r], o, 64);
      p2[r] += __shfl_xor(p2[r], o, 64);
    }
  if (c16 == 0) {
    const int row = n0 + w * 16 + q * 4;
#pragma unroll
    for (int r = 0; r < 4; r++) {
      s1[(h << 12) + row + r] = p1[r];
      s2[(h << 12) + row + r] = p2[r];
    }
  }
}

// ---------- fused layer-1: per node, 8 waves = 8 heads attention + Wh2 + s1b/s2b
__global__ __launch_bounds__(512) void layer1_node(
    const float* __restrict__ Wh, const float* __restrict__ s1,
    const float* __restrict__ s2, const int* __restrict__ cols,
    const int* __restrict__ cnts, const float* __restrict__ W_out,
    const float* __restrict__ a_out, float* __restrict__ Wh2,
    float* __restrict__ s1b, float* __restrict__ s2b) {
  __shared__ float hrow[NHEADS * NHID];
  __shared__ float part[NHEADS][44];
  const int i = blockIdx.x;
  const int h = threadIdx.x >> 6, lane = threadIdx.x & 63;
  const int cnt = cnts[i];
  const float s1i = s1[(h << 12) + i];
  float e0 = -1e30f;
  int j0 = 0;
  if (lane < cnt) {
    j0 = cols[i * ELLW + lane];
    float t = s1i + s2[(h << 12) + j0];
    e0 = t > 0.f ? t : ALPHA * t;
  }
  const float m = wred_max(e0);
  float p = (lane < cnt) ? expf(e0 - m) : 0.f;
  const float S = wred_sum(p);
  p *= 1.f / S;
  // gather: shfl-broadcast p/j from lane t, accumulate Wh rows
  const float* Whh = Wh + ((size_t)h << 12) * NHID;
  float acc = 0.f;
  for (int t = 0; t < cnt; t++) {
    const float pt = __shfl(p, t, 64);
    const int jt = __shfl(j0, t, 64);
    acc += pt * Whh[(size_t)jt * NHID + lane];
  }
  const float o = acc > 0.f ? acc : expf(acc) - 1.f;  // ELU
  hrow[h * NHID + lane] = o;
  __syncthreads();
  // Wh2 = hrow @ W_out, k-range [64h, 64h+64) per wave
  float pa = 0.f;
  if (lane < NCLASS) {
    const float* wo = W_out + (h * NHID) * NCLASS + lane;
#pragma unroll
    for (int kk = 0; kk < NHID; kk++) pa += hrow[h * NHID + kk] * wo[kk * NCLASS];
    part[h][lane] = pa;
  }
  __syncthreads();
  if (h == 0) {
    float fin = 0.f;
    if (lane < NCLASS) {
#pragma unroll
      for (int w2 = 0; w2 < NHEADS; w2++) fin += part[w2][lane];
    }
    const float r1 = wred_sum((lane < NCLASS) ? fin * a_out[lane] : 0.f);
    const float r2 = wred_sum((lane < NCLASS) ? fin * a_out[NCLASS + lane] : 0.f);
    if (lane < NCLASS) Wh2[(size_t)i * NCLASS + lane] = fin;
    if (lane == 0) { s1b[i] = r1; s2b[i] = r2; }
  }
}

// ----------------- layer-2 sparse attention + ELU + log_softmax -> out (fp32)
__global__ __launch_bounds__(256) void att2_kernel(const float* __restrict__ Wh2,
                                                   const float* __restrict__ s1b,
                                                   const float* __restrict__ s2b,
                                                   const int* __restrict__ cols,
                                                   const int* __restrict__ cnts,
                                                   float* __restrict__ out) {
  const int w = threadIdx.x >> 6, lane = threadIdx.x & 63;
  const int i = blockIdx.x * 4 + w;
  const int cnt = cnts[i];
  const float s1i = s1b[i];
  float e0 = -1e30f;
  int j0 = 0;
  if (lane < cnt) {
    j0 = cols[i * ELLW + lane];
    float t = s1i + s2b[j0];
    e0 = t > 0.f ? t : ALPHA * t;
  }
  const float m = wred_max(e0);
  float p = (lane < cnt) ? expf(e0 - m) : 0.f;
  const float S = wred_sum(p);
  p *= 1.f / S;
  float acc = 0.f;
  for (int t = 0; t < cnt; t++) {
    const float pt = __shfl(p, t, 64);
    const int jt = __shfl(j0, t, 64);
    if (lane < NCLASS) acc += pt * Wh2[(size_t)jt * NCLASS + lane];
  }
  const float o = acc > 0.f ? acc : expf(acc) - 1.f;  // ELU
  const float vv = (lane < NCLASS) ? o : -1e30f;
  const float mm = wred_max(vv);
  const float ex = (lane < NCLASS) ? expf(o - mm) : 0.f;
  const float SS = wred_sum(ex);
  if (lane < NCLASS) out[(size_t)i * NCLASS + lane] = o - mm - logf(SS);
}

// ---------------------------------------------------------------------------
extern "C" void kernel_launch(void* const* d_in, const int* in_sizes, int n_in,
                              void* d_out, int out_size, void* d_ws, size_t ws_size,
                              hipStream_t stream) {
  const float* x       = (const float*)d_in[0];   // (4096, 512)
  const float* adj     = (const float*)d_in[1];   // (4096, 4096)
  const float* W_heads = (const float*)d_in[2];   // (8, 512, 64)
  const float* a_heads = (const float*)d_in[3];   // (8, 128, 1)
  const float* W_out   = (const float*)d_in[4];   // (512, 41)
  const float* a_out   = (const float*)d_in[5];   // (82, 1)
  float* out = (float*)d_out;                     // (4096, 41)

  // workspace layout (~19 MB)
  float* ws   = (float*)d_ws;
  float* Wh   = ws;                                  // 8*4096*64
  float* s1   = Wh + (size_t)NHEADS * N * NHID;      // 8*4096
  float* s2   = s1 + NHEADS * N;                     // 8*4096
  float* Wh2  = s2 + NHEADS * N;                     // 4096*41
  float* s1b  = Wh2 + (size_t)N * NCLASS;            // 4096
  float* s2b  = s1b + N;                             // 4096
  int* cnts   = (int*)(s2b + N);                     // 4096
  int* cols   = cnts + N;                            // 4096*64
  short* Xhi  = (short*)(cols + N * ELLW);           // 4096*512
  short* Xlo  = Xhi + (size_t)N * NFEAT;             // 4096*512
  short* Wthi = Xlo + (size_t)N * NFEAT;             // 8*64*512
  short* Wtlo = Wthi + (size_t)NHEADS * NHID * NFEAT;// 8*64*512

  hipLaunchKernelGGL(build_ell, dim3(N), dim3(256), 0, stream, adj, cols, cnts);
  hipLaunchKernelGGL(prep, dim3(3072), dim3(256), 0, stream, x, W_heads, Xhi, Xlo, Wthi, Wtlo);
  hipLaunchKernelGGL(wh_gemm_mfma, dim3(NHEADS, N / 64), dim3(256), 0, stream,
                     Xhi, Xlo, Wthi, Wtlo, a_heads, Wh, s1, s2);
  hipLaunchKernelGGL(layer1_node, dim3(N), dim3(512), 0, stream,
                     Wh, s1, s2, cols, cnts, W_out, a_out, Wh2, s1b, s2b);
  hipLaunchKernelGGL(att2_kernel, dim3(N / 4), dim3(256), 0, stream,
                     Wh2, s1b, s2b, cols, cnts, out);
}

// Round 5
// 171.682 us; speedup vs baseline: 1.1373x; 1.1373x over previous
//
#include <hip/hip_runtime.h>
#include <hip/hip_bf16.h>
#include <math.h>

// GAT, N=4096, NFEAT=512, NHID=64, NHEADS=8, NCLASS=41, EDGE_P=0.004.
// Adjacency ~17 nnz/row -> both attention layers are exactly sparse.
// gemm1 (x@W_heads) and gemm2 (h@W_out) use bf16 MFMA with split-bf16 (hi+lo)
// 3-term products for fp32-grade accuracy. att1 gathers 4 neighbors/iter with
// float4 loads (latency chain /4) and emits h pre-split to bf16 for gemm2.

#define N 4096
#define NFEAT 512
#define NHID 64
#define NHEADS 8
#define NCLASS 41
#define NCPAD 48
#define ALPHA 0.2f
#define ELLW 64   // Binomial(4096,0.004): mean 16.4, P(cnt>64) ~ 1e-18

using short8  = __attribute__((ext_vector_type(8))) short;
using floatx4 = __attribute__((ext_vector_type(4))) float;

__device__ __forceinline__ float wred_max(float v) {
#pragma unroll
  for (int o = 32; o; o >>= 1) v = fmaxf(v, __shfl_xor(v, o, 64));
  return v;
}
__device__ __forceinline__ float wred_sum(float v) {
#pragma unroll
  for (int o = 32; o; o >>= 1) v += __shfl_xor(v, o, 64);
  return v;
}

__device__ __forceinline__ void split_bf16(float v, short& hi, short& lo) {
  __hip_bfloat16 hb = __float2bfloat16(v);
  float hf = __bfloat162float(hb);
  __hip_bfloat16 lb = __float2bfloat16(v - hf);
  hi = *reinterpret_cast<short*>(&hb);
  lo = *reinterpret_cast<short*>(&lb);
}

// ---------------------------------------------------------------- build ELL
__global__ __launch_bounds__(256) void build_ell(const float* __restrict__ adj,
                                                 int* __restrict__ cols,
                                                 int* __restrict__ cnts) {
  __shared__ int c;
  const int row = blockIdx.x;
  if (threadIdx.x == 0) c = 0;
  __syncthreads();
  const float4* arow = (const float4*)(adj + (size_t)row * N);
  for (int j4 = threadIdx.x; j4 < N / 4; j4 += 256) {
    float4 v = arow[j4];
    if (v.x > 0.f) { int p = atomicAdd(&c, 1); if (p < ELLW) cols[row * ELLW + p] = j4 * 4 + 0; }
    if (v.y > 0.f) { int p = atomicAdd(&c, 1); if (p < ELLW) cols[row * ELLW + p] = j4 * 4 + 1; }
    if (v.z > 0.f) { int p = atomicAdd(&c, 1); if (p < ELLW) cols[row * ELLW + p] = j4 * 4 + 2; }
    if (v.w > 0.f) { int p = atomicAdd(&c, 1); if (p < ELLW) cols[row * ELLW + p] = j4 * 4 + 3; }
  }
  __syncthreads();
  if (threadIdx.x == 0) cnts[row] = min(c, ELLW);
}

// ---- prep: split x -> bf16 hi/lo; split+transpose W_heads; split+T W_out
// blocks [0,2048): x. [2048,3072): W_heads. [3072,3168): W_out (pad 41->48).
__global__ __launch_bounds__(256) void prep(const float* __restrict__ x,
                                            const float* __restrict__ W,
                                            const float* __restrict__ W_out,
                                            short* __restrict__ Xhi,
                                            short* __restrict__ Xlo,
                                            short* __restrict__ Wthi,
                                            short* __restrict__ Wtlo,
                                            short* __restrict__ WOhi,
                                            short* __restrict__ WOlo) {
  if (blockIdx.x < 2048) {
    const int t = blockIdx.x * 256 + threadIdx.x;      // float4 index
    const float4 v = ((const float4*)x)[t];
    short h0, l0, h1, l1, h2, l2, h3, l3;
    split_bf16(v.x, h0, l0);
    split_bf16(v.y, h1, l1);
    split_bf16(v.z, h2, l2);
    split_bf16(v.w, h3, l3);
    ((short4*)Xhi)[t] = make_short4(h0, h1, h2, h3);
    ((short4*)Xlo)[t] = make_short4(l0, l1, l2, l3);
  } else if (blockIdx.x < 3072) {
    const int t = (blockIdx.x - 2048) * 256 + threadIdx.x;  // 0..262143
    const int h = t >> 15, r = t & 32767;
    const int d = r >> 9, k = r & 511;                 // write-coalesced
    float v = W[(size_t)h * 32768 + (size_t)k * 64 + d];
    short hi, lo;
    split_bf16(v, hi, lo);
    Wthi[(size_t)h * 32768 + d * 512 + k] = hi;
    Wtlo[(size_t)h * 32768 + d * 512 + k] = lo;
  } else {
    const int t = (blockIdx.x - 3072) * 256 + threadIdx.x;  // 0..24575
    const int c = t >> 9, k = t & 511;
    float v = (c < NCLASS) ? W_out[(size_t)k * NCLASS + c] : 0.f;
    short hi, lo;
    split_bf16(v, hi, lo);
    WOhi[c * 512 + k] = hi;
    WOlo[c * 512 + k] = lo;
  }
}

// ----------------- Wh = x @ W_heads via split-bf16 MFMA; fused s1/s2 epilogue
__global__ __launch_bounds__(256) void wh_gemm_mfma(
    const short* __restrict__ Xhi, const short* __restrict__ Xlo,
    const short* __restrict__ Wthi, const short* __restrict__ Wtlo,
    const float* __restrict__ a_heads,
    float* __restrict__ Wh, float* __restrict__ s1, float* __restrict__ s2) {
  __shared__ __align__(16) short Ahi[64 * 72];
  __shared__ __align__(16) short Alo[64 * 72];
  __shared__ __align__(16) short Bhi[64 * 72];
  __shared__ __align__(16) short Blo[64 * 72];
  const int h = blockIdx.x;
  const int n0 = blockIdx.y * 64;
  const int tid = threadIdx.x;
  const int w = tid >> 6, L = tid & 63;

  floatx4 acc[4];
#pragma unroll
  for (int f = 0; f < 4; f++) acc[f] = (floatx4){0.f, 0.f, 0.f, 0.f};

  for (int k0 = 0; k0 < NFEAT; k0 += 64) {
    __syncthreads();
#pragma unroll
    for (int i = 0; i < 2; i++) {
      const int g = tid + 256 * i;       // (row, 8-elem k group)
      const int row = g >> 3, kg = (g & 7) * 8;
      const size_t asrc = (size_t)(n0 + row) * NFEAT + k0 + kg;
      *(uint4*)&Ahi[row * 72 + kg] = *(const uint4*)&Xhi[asrc];
      *(uint4*)&Alo[row * 72 + kg] = *(const uint4*)&Xlo[asrc];
      const size_t bsrc = (size_t)h * 32768 + (size_t)row * 512 + k0 + kg;
      *(uint4*)&Bhi[row * 72 + kg] = *(const uint4*)&Wthi[bsrc];
      *(uint4*)&Blo[row * 72 + kg] = *(const uint4*)&Wtlo[bsrc];
    }
    __syncthreads();
#pragma unroll
    for (int ks = 0; ks < 2; ks++) {
      const int koff = ks * 32 + (L >> 4) * 8;
      short8 ahi = *(const short8*)&Ahi[(w * 16 + (L & 15)) * 72 + koff];
      short8 alo = *(const short8*)&Alo[(w * 16 + (L & 15)) * 72 + koff];
#pragma unroll
      for (int f = 0; f < 4; f++) {
        short8 bhi = *(const short8*)&Bhi[(f * 16 + (L & 15)) * 72 + koff];
        short8 blo = *(const short8*)&Blo[(f * 16 + (L & 15)) * 72 + koff];
        acc[f] = __builtin_amdgcn_mfma_f32_16x16x32_bf16(ahi, bhi, acc[f], 0, 0, 0);
        acc[f] = __builtin_amdgcn_mfma_f32_16x16x32_bf16(ahi, blo, acc[f], 0, 0, 0);
        acc[f] = __builtin_amdgcn_mfma_f32_16x16x32_bf16(alo, bhi, acc[f], 0, 0, 0);
      }
    }
  }

  const int q = L >> 4, c16 = L & 15;
  float a1v[4], a2v[4];
#pragma unroll
  for (int f = 0; f < 4; f++) {
    a1v[f] = a_heads[h * 128 + f * 16 + c16];
    a2v[f] = a_heads[h * 128 + 64 + f * 16 + c16];
  }
  float p1[4] = {0.f, 0.f, 0.f, 0.f}, p2[4] = {0.f, 0.f, 0.f, 0.f};
#pragma unroll
  for (int f = 0; f < 4; f++)
#pragma unroll
    for (int r = 0; r < 4; r++) {
      const float vv = acc[f][r];
      const int row = n0 + w * 16 + q * 4 + r;
      Wh[((size_t)(h << 12) + row) * NHID + f * 16 + c16] = vv;
      p1[r] += vv * a1v[f];
      p2[r] += vv * a2v[f];
    }
#pragma unroll
  for (int r = 0; r < 4; r++)
#pragma unroll
    for (int o = 1; o < 16; o <<= 1) {
      p1[r] += __shfl_xor(p1[r], o, 64);
      p2[r] += __shfl_xor(p2[r], o, 64);
    }
  if (c16 == 0) {
    const int row = n0 + w * 16 + q * 4;
#pragma unroll
    for (int r = 0; r < 4; r++) {
      s1[(h << 12) + row + r] = p1[r];
      s2[(h << 12) + row + r] = p2[r];
    }
  }
}

// ---- layer-1 attention: wave per (i,h); 4-neighbor-parallel float4 gather;
//      ELU; emit h as split bf16 (Hhi/Hlo) laid out [node][head*64+d].
__global__ __launch_bounds__(256) void att1_kernel(
    const float* __restrict__ Wh, const float* __restrict__ s1,
    const float* __restrict__ s2, const int* __restrict__ cols,
    const int* __restrict__ cnts, short* __restrict__ Hhi,
    short* __restrict__ Hlo) {
  __shared__ float pj[4][68];
  __shared__ int jj[4][68];
  const int w = threadIdx.x >> 6, lane = threadIdx.x & 63;
  const int pair = blockIdx.x * 4 + w;
  const int h = pair >> 12, i = pair & (N - 1);
  const int cnt = cnts[i];
  const float s1i = s1[(h << 12) + i];
  const float* s2h = s2 + (h << 12);
  float e0 = -1e30f;
  int j0 = 0;
  if (lane < cnt) {
    j0 = cols[i * ELLW + lane];
    float t = s1i + s2h[j0];
    e0 = t > 0.f ? t : ALPHA * t;
  }
  const float m = wred_max(e0);
  float p = (lane < cnt) ? expf(e0 - m) : 0.f;
  const float S = wred_sum(p);
  p *= 1.f / S;                       // lanes >= cnt hold exactly 0
  pj[w][lane] = p;
  jj[w][lane] = (lane < cnt) ? j0 : 0;
  if (lane < 4) { pj[w][64 + lane] = 0.f; jj[w][64 + lane] = 0; }  // overrun pad
  __syncthreads();
  // gather: 4 neighbors in flight; group grp handles neighbor t0+grp,
  // its 16 lanes load a float4 slice of the 64-float Wh row (256 B/group).
  const int grp = lane >> 4, c4 = lane & 15;
  const float* Whh = Wh + (((size_t)h << 12)) * NHID;
  float4 acc = make_float4(0.f, 0.f, 0.f, 0.f);
  for (int t0 = 0; t0 < cnt; t0 += 4) {
    const float pt = pj[w][t0 + grp];
    const int jt = jj[w][t0 + grp];
    const float4 v = *(const float4*)&Whh[(size_t)jt * NHID + c4 * 4];
    acc.x += pt * v.x; acc.y += pt * v.y; acc.z += pt * v.z; acc.w += pt * v.w;
  }
#pragma unroll
  for (int off = 16; off <= 32; off <<= 1) {
    acc.x += __shfl_xor(acc.x, off, 64);
    acc.y += __shfl_xor(acc.y, off, 64);
    acc.z += __shfl_xor(acc.z, off, 64);
    acc.w += __shfl_xor(acc.w, off, 64);
  }
  if (grp == 0) {
    const float o0 = acc.x > 0.f ? acc.x : expf(acc.x) - 1.f;
    const float o1 = acc.y > 0.f ? acc.y : expf(acc.y) - 1.f;
    const float o2 = acc.z > 0.f ? acc.z : expf(acc.z) - 1.f;
    const float o3 = acc.w > 0.f ? acc.w : expf(acc.w) - 1.f;
    short h0, l0, h1, l1, h2, l2, h3, l3;
    split_bf16(o0, h0, l0);
    split_bf16(o1, h1, l1);
    split_bf16(o2, h2, l2);
    split_bf16(o3, h3, l3);
    const size_t base = (size_t)i * 512 + h * 64 + c4 * 4;
    *(short4*)&Hhi[base] = make_short4(h0, h1, h2, h3);
    *(short4*)&Hlo[base] = make_short4(l0, l1, l2, l3);
  }
}

// ---- gemm2: Wh2 = h @ W_out (split-bf16 MFMA, cols padded to 48);
//      fused s1b/s2b = Wh2 . a_out halves.
__global__ __launch_bounds__(256) void gemm2_mfma(
    const short* __restrict__ Hhi, const short* __restrict__ Hlo,
    const short* __restrict__ WOhi, const short* __restrict__ WOlo,
    const float* __restrict__ a_out,
    float* __restrict__ Wh2, float* __restrict__ s1b, float* __restrict__ s2b) {
  __shared__ __align__(16) short Ahi[64 * 72];
  __shared__ __align__(16) short Alo[64 * 72];
  __shared__ __align__(16) short Bhi[NCPAD * 72];
  __shared__ __align__(16) short Blo[NCPAD * 72];
  const int n0 = blockIdx.x * 64;
  const int tid = threadIdx.x;
  const int w = tid >> 6, L = tid & 63;

  floatx4 acc[3];
#pragma unroll
  for (int f = 0; f < 3; f++) acc[f] = (floatx4){0.f, 0.f, 0.f, 0.f};

  for (int k0 = 0; k0 < 512; k0 += 64) {
    __syncthreads();
#pragma unroll
    for (int i = 0; i < 2; i++) {
      const int g = tid + 256 * i;       // 512 A-granules
      const int row = g >> 3, kg = (g & 7) * 8;
      const size_t asrc = (size_t)(n0 + row) * 512 + k0 + kg;
      *(uint4*)&Ahi[row * 72 + kg] = *(const uint4*)&Hhi[asrc];
      *(uint4*)&Alo[row * 72 + kg] = *(const uint4*)&Hlo[asrc];
      if (g < NCPAD * 8) {               // 384 B-granules
        const size_t bsrc = (size_t)row * 512 + k0 + kg;
        *(uint4*)&Bhi[row * 72 + kg] = *(const uint4*)&WOhi[bsrc];
        *(uint4*)&Blo[row * 72 + kg] = *(const uint4*)&WOlo[bsrc];
      }
    }
    __syncthreads();
#pragma unroll
    for (int ks = 0; ks < 2; ks++) {
      const int koff = ks * 32 + (L >> 4) * 8;
      short8 ahi = *(const short8*)&Ahi[(w * 16 + (L & 15)) * 72 + koff];
      short8 alo = *(const short8*)&Alo[(w * 16 + (L & 15)) * 72 + koff];
#pragma unroll
      for (int f = 0; f < 3; f++) {
        short8 bhi = *(const short8*)&Bhi[(f * 16 + (L & 15)) * 72 + koff];
        short8 blo = *(const short8*)&Blo[(f * 16 + (L & 15)) * 72 + koff];
        acc[f] = __builtin_amdgcn_mfma_f32_16x16x32_bf16(ahi, bhi, acc[f], 0, 0, 0);
        acc[f] = __builtin_amdgcn_mfma_f32_16x16x32_bf16(ahi, blo, acc[f], 0, 0, 0);
        acc[f] = __builtin_amdgcn_mfma_f32_16x16x32_bf16(alo, bhi, acc[f], 0, 0, 0);
      }
    }
  }

  const int q = L >> 4, c16 = L & 15;
  float a1v[3], a2v[3];
#pragma unroll
  for (int f = 0; f < 3; f++) {
    const int col = f * 16 + c16;
    a1v[f] = (col < NCLASS) ? a_out[col] : 0.f;
    a2v[f] = (col < NCLASS) ? a_out[NCLASS + col] : 0.f;
  }
  float p1[4] = {0.f, 0.f, 0.f, 0.f}, p2[4] = {0.f, 0.f, 0.f, 0.f};
#pragma unroll
  for (int f = 0; f < 3; f++)
#pragma unroll
    for (int r = 0; r < 4; r++) {
      const float vv = acc[f][r];
      const int col = f * 16 + c16;
      const int row = n0 + w * 16 + q * 4 + r;
      if (col < NCLASS) Wh2[(size_t)row * NCLASS + col] = vv;
      p1[r] += vv * a1v[f];
      p2[r] += vv * a2v[f];
    }
#pragma unroll
  for (int r = 0; r < 4; r++)
#pragma unroll
    for (int o = 1; o < 16; o <<= 1) {
      p1[r] += __shfl_xor(p1[r], o, 64);
      p2[r] += __shfl_xor(p2[r], o, 64);
    }
  if (c16 == 0) {
    const int row = n0 + w * 16 + q * 4;
#pragma unroll
    for (int r = 0; r < 4; r++) {
      s1b[row + r] = p1[r];
      s2b[row + r] = p2[r];
    }
  }
}

// ----------------- layer-2 sparse attention + ELU + log_softmax -> out (fp32)
__global__ __launch_bounds__(256) void att2_kernel(const float* __restrict__ Wh2,
                                                   const float* __restrict__ s1b,
                                                   const float* __restrict__ s2b,
                                                   const int* __restrict__ cols,
                                                   const int* __restrict__ cnts,
                                                   float* __restrict__ out) {
  __shared__ float pj[4][64];
  __shared__ int jj[4][64];
  const int w = threadIdx.x >> 6, lane = threadIdx.x & 63;
  const int i = blockIdx.x * 4 + w;
  const int cnt = cnts[i];
  const float s1i = s1b[i];
  float e0 = -1e30f;
  int j0 = 0;
  if (lane < cnt) {
    j0 = cols[i * ELLW + lane];
    float t = s1i + s2b[j0];
    e0 = t > 0.f ? t : ALPHA * t;
  }
  const float m = wred_max(e0);
  float p = (lane < cnt) ? expf(e0 - m) : 0.f;
  const float S = wred_sum(p);
  p *= 1.f / S;
  pj[w][lane] = p;
  jj[w][lane] = (lane < cnt) ? j0 : 0;
  __syncthreads();
  float acc = 0.f;
  for (int t = 0; t < cnt; t++) {
    const float pt = pj[w][t];
    const int jt = jj[w][t];
    if (lane < NCLASS) acc += pt * Wh2[(size_t)jt * NCLASS + lane];
  }
  const float o = acc > 0.f ? acc : expf(acc) - 1.f;  // ELU
  const float vv = (lane < NCLASS) ? o : -1e30f;
  const float mm = wred_max(vv);
  const float ex = (lane < NCLASS) ? expf(o - mm) : 0.f;
  const float SS = wred_sum(ex);
  if (lane < NCLASS) out[(size_t)i * NCLASS + lane] = o - mm - logf(SS);
}

// ---------------------------------------------------------------------------
extern "C" void kernel_launch(void* const* d_in, const int* in_sizes, int n_in,
                              void* d_out, int out_size, void* d_ws, size_t ws_size,
                              hipStream_t stream) {
  const float* x       = (const float*)d_in[0];   // (4096, 512)
  const float* adj     = (const float*)d_in[1];   // (4096, 4096)
  const float* W_heads = (const float*)d_in[2];   // (8, 512, 64)
  const float* a_heads = (const float*)d_in[3];   // (8, 128, 1)
  const float* W_out   = (const float*)d_in[4];   // (512, 41)
  const float* a_out   = (const float*)d_in[5];   // (82, 1)
  float* out = (float*)d_out;                     // (4096, 41)

  // workspace layout (~29 MB)
  float* ws   = (float*)d_ws;
  float* Wh   = ws;                                  // 8*4096*64
  float* s1   = Wh + (size_t)NHEADS * N * NHID;      // 8*4096
  float* s2   = s1 + NHEADS * N;                     // 8*4096
  float* Wh2  = s2 + NHEADS * N;                     // 4096*41
  float* s1b  = Wh2 + (size_t)N * NCLASS;            // 4096
  float* s2b  = s1b + N;                             // 4096
  int* cnts   = (int*)(s2b + N);                     // 4096
  int* cols   = cnts + N;                            // 4096*64
  short* Xhi  = (short*)(cols + N * ELLW);           // 4096*512
  short* Xlo  = Xhi + (size_t)N * NFEAT;             // 4096*512
  short* Wthi = Xlo + (size_t)N * NFEAT;             // 8*64*512
  short* Wtlo = Wthi + (size_t)NHEADS * NHID * NFEAT;// 8*64*512
  short* WOhi = Wtlo + (size_t)NHEADS * NHID * NFEAT;// 48*512
  short* WOlo = WOhi + (size_t)NCPAD * 512;          // 48*512
  short* Hhi  = WOlo + (size_t)NCPAD * 512;          // 4096*512
  short* Hlo  = Hhi + (size_t)N * NFEAT;             // 4096*512

  hipLaunchKernelGGL(build_ell, dim3(N), dim3(256), 0, stream, adj, cols, cnts);
  hipLaunchKernelGGL(prep, dim3(3168), dim3(256), 0, stream,
                     x, W_heads, W_out, Xhi, Xlo, Wthi, Wtlo, WOhi, WOlo);
  hipLaunchKernelGGL(wh_gemm_mfma, dim3(NHEADS, N / 64), dim3(256), 0, stream,
                     Xhi, Xlo, Wthi, Wtlo, a_heads, Wh, s1, s2);
  hipLaunchKernelGGL(att1_kernel, dim3(NHEADS * N / 4), dim3(256), 0, stream,
                     Wh, s1, s2, cols, cnts, Hhi, Hlo);
  hipLaunchKernelGGL(gemm2_mfma, dim3(N / 64), dim3(256), 0, stream,
                     Hhi, Hlo, WOhi, WOlo, a_out, Wh2, s1b, s2b);
  hipLaunchKernelGGL(att2_kernel, dim3(N / 4), dim3(256), 0, stream,
                     Wh2, s1b, s2b, cols, cnts, out);
}

// Round 6
// 170.222 us; speedup vs baseline: 1.1470x; 1.0086x over previous
//
#include <hip/hip_runtime.h>
#include <hip/hip_bf16.h>
#include <math.h>

// GAT, N=4096, NFEAT=512, NHID=64, NHEADS=8, NCLASS=41, EDGE_P=0.004.
// Adjacency ~17 nnz/row -> both attention layers are exactly sparse.
// gemm1 (x@W_heads) and gemm2 (h@W_out) use bf16 MFMA with split-bf16 (hi+lo)
// 3-term products for fp32-grade accuracy. att1 gathers 4 neighbors/iter with
// float4 loads and emits h pre-split to bf16 for gemm2.
// setup = build_ell + all input splitting/transposition fused in one launch.

#define N 4096
#define NFEAT 512
#define NHID 64
#define NHEADS 8
#define NCLASS 41
#define NCPAD 48
#define ALPHA 0.2f
#define ELLW 64   // Binomial(4096,0.004): mean 16.4, P(cnt>64) ~ 1e-18

using short8  = __attribute__((ext_vector_type(8))) short;
using floatx4 = __attribute__((ext_vector_type(4))) float;

__device__ __forceinline__ float wred_max(float v) {
#pragma unroll
  for (int o = 32; o; o >>= 1) v = fmaxf(v, __shfl_xor(v, o, 64));
  return v;
}
__device__ __forceinline__ float wred_sum(float v) {
#pragma unroll
  for (int o = 32; o; o >>= 1) v += __shfl_xor(v, o, 64);
  return v;
}

__device__ __forceinline__ void split_bf16(float v, short& hi, short& lo) {
  __hip_bfloat16 hb = __float2bfloat16(v);
  float hf = __bfloat162float(hb);
  __hip_bfloat16 lb = __float2bfloat16(v - hf);
  hi = *reinterpret_cast<short*>(&hb);
  lo = *reinterpret_cast<short*>(&lb);
}

// ---- setup: fused prep (x split, W_heads split+T, W_out split+T) + build_ell
// blocks [0,2048): x. [2048,3072): W_heads. [3072,3168): W_out. [3168,7264): adj.
__global__ __launch_bounds__(256) void setup(const float* __restrict__ x,
                                             const float* __restrict__ W,
                                             const float* __restrict__ W_out,
                                             const float* __restrict__ adj,
                                             short* __restrict__ Xhi,
                                             short* __restrict__ Xlo,
                                             short* __restrict__ Wthi,
                                             short* __restrict__ Wtlo,
                                             short* __restrict__ WOhi,
                                             short* __restrict__ WOlo,
                                             int* __restrict__ cols,
                                             int* __restrict__ cnts) {
  if (blockIdx.x >= 3168) {
    // -------- build ELL neighbor lists
    __shared__ int c;
    const int row = blockIdx.x - 3168;
    if (threadIdx.x == 0) c = 0;
    __syncthreads();
    const float4* arow = (const float4*)(adj + (size_t)row * N);
    for (int j4 = threadIdx.x; j4 < N / 4; j4 += 256) {
      float4 v = arow[j4];
      if (v.x > 0.f) { int p = atomicAdd(&c, 1); if (p < ELLW) cols[row * ELLW + p] = j4 * 4 + 0; }
      if (v.y > 0.f) { int p = atomicAdd(&c, 1); if (p < ELLW) cols[row * ELLW + p] = j4 * 4 + 1; }
      if (v.z > 0.f) { int p = atomicAdd(&c, 1); if (p < ELLW) cols[row * ELLW + p] = j4 * 4 + 2; }
      if (v.w > 0.f) { int p = atomicAdd(&c, 1); if (p < ELLW) cols[row * ELLW + p] = j4 * 4 + 3; }
    }
    __syncthreads();
    if (threadIdx.x == 0) cnts[row] = min(c, ELLW);
  } else if (blockIdx.x < 2048) {
    const int t = blockIdx.x * 256 + threadIdx.x;      // float4 index
    const float4 v = ((const float4*)x)[t];
    short h0, l0, h1, l1, h2, l2, h3, l3;
    split_bf16(v.x, h0, l0);
    split_bf16(v.y, h1, l1);
    split_bf16(v.z, h2, l2);
    split_bf16(v.w, h3, l3);
    ((short4*)Xhi)[t] = make_short4(h0, h1, h2, h3);
    ((short4*)Xlo)[t] = make_short4(l0, l1, l2, l3);
  } else if (blockIdx.x < 3072) {
    const int t = (blockIdx.x - 2048) * 256 + threadIdx.x;  // 0..262143
    const int h = t >> 15, r = t & 32767;
    const int d = r >> 9, k = r & 511;                 // write-coalesced
    float v = W[(size_t)h * 32768 + (size_t)k * 64 + d];
    short hi, lo;
    split_bf16(v, hi, lo);
    Wthi[(size_t)h * 32768 + d * 512 + k] = hi;
    Wtlo[(size_t)h * 32768 + d * 512 + k] = lo;
  } else {
    const int t = (blockIdx.x - 3072) * 256 + threadIdx.x;  // 0..24575
    const int c = t >> 9, k = t & 511;
    float v = (c < NCLASS) ? W_out[(size_t)k * NCLASS + c] : 0.f;
    short hi, lo;
    split_bf16(v, hi, lo);
    WOhi[c * 512 + k] = hi;
    WOlo[c * 512 + k] = lo;
  }
}

// ----------------- Wh = x @ W_heads via split-bf16 MFMA; fused s1/s2 epilogue
__global__ __launch_bounds__(256) void wh_gemm_mfma(
    const short* __restrict__ Xhi, const short* __restrict__ Xlo,
    const short* __restrict__ Wthi, const short* __restrict__ Wtlo,
    const float* __restrict__ a_heads,
    float* __restrict__ Wh, float* __restrict__ s1, float* __restrict__ s2) {
  __shared__ __align__(16) short Ahi[64 * 72];
  __shared__ __align__(16) short Alo[64 * 72];
  __shared__ __align__(16) short Bhi[64 * 72];
  __shared__ __align__(16) short Blo[64 * 72];
  const int h = blockIdx.x;
  const int n0 = blockIdx.y * 64;
  const int tid = threadIdx.x;
  const int w = tid >> 6, L = tid & 63;

  floatx4 acc[4];
#pragma unroll
  for (int f = 0; f < 4; f++) acc[f] = (floatx4){0.f, 0.f, 0.f, 0.f};

  for (int k0 = 0; k0 < NFEAT; k0 += 64) {
    __syncthreads();
#pragma unroll
    for (int i = 0; i < 2; i++) {
      const int g = tid + 256 * i;       // (row, 8-elem k group)
      const int row = g >> 3, kg = (g & 7) * 8;
      const size_t asrc = (size_t)(n0 + row) * NFEAT + k0 + kg;
      *(uint4*)&Ahi[row * 72 + kg] = *(const uint4*)&Xhi[asrc];
      *(uint4*)&Alo[row * 72 + kg] = *(const uint4*)&Xlo[asrc];
      const size_t bsrc = (size_t)h * 32768 + (size_t)row * 512 + k0 + kg;
      *(uint4*)&Bhi[row * 72 + kg] = *(const uint4*)&Wthi[bsrc];
      *(uint4*)&Blo[row * 72 + kg] = *(const uint4*)&Wtlo[bsrc];
    }
    __syncthreads();
#pragma unroll
    for (int ks = 0; ks < 2; ks++) {
      const int koff = ks * 32 + (L >> 4) * 8;
      short8 ahi = *(const short8*)&Ahi[(w * 16 + (L & 15)) * 72 + koff];
      short8 alo = *(const short8*)&Alo[(w * 16 + (L & 15)) * 72 + koff];
#pragma unroll
      for (int f = 0; f < 4; f++) {
        short8 bhi = *(const short8*)&Bhi[(f * 16 + (L & 15)) * 72 + koff];
        short8 blo = *(const short8*)&Blo[(f * 16 + (L & 15)) * 72 + koff];
        acc[f] = __builtin_amdgcn_mfma_f32_16x16x32_bf16(ahi, bhi, acc[f], 0, 0, 0);
        acc[f] = __builtin_amdgcn_mfma_f32_16x16x32_bf16(ahi, blo, acc[f], 0, 0, 0);
        acc[f] = __builtin_amdgcn_mfma_f32_16x16x32_bf16(alo, bhi, acc[f], 0, 0, 0);
      }
    }
  }

  const int q = L >> 4, c16 = L & 15;
  float a1v[4], a2v[4];
#pragma unroll
  for (int f = 0; f < 4; f++) {
    a1v[f] = a_heads[h * 128 + f * 16 + c16];
    a2v[f] = a_heads[h * 128 + 64 + f * 16 + c16];
  }
  float p1[4] = {0.f, 0.f, 0.f, 0.f}, p2[4] = {0.f, 0.f, 0.f, 0.f};
#pragma unroll
  for (int f = 0; f < 4; f++)
#pragma unroll
    for (int r = 0; r < 4; r++) {
      const float vv = acc[f][r];
      const int row = n0 + w * 16 + q * 4 + r;
      Wh[((size_t)(h << 12) + row) * NHID + f * 16 + c16] = vv;
      p1[r] += vv * a1v[f];
      p2[r] += vv * a2v[f];
    }
#pragma unroll
  for (int r = 0; r < 4; r++)
#pragma unroll
    for (int o = 1; o < 16; o <<= 1) {
      p1[r] += __shfl_xor(p1[r], o, 64);
      p2[r] += __shfl_xor(p2[r], o, 64);
    }
  if (c16 == 0) {
    const int row = n0 + w * 16 + q * 4;
#pragma unroll
    for (int r = 0; r < 4; r++) {
      s1[(h << 12) + row + r] = p1[r];
      s2[(h << 12) + row + r] = p2[r];
    }
  }
}

// ---- layer-1 attention: wave per (i,h); 4-neighbor-parallel float4 gather;
//      ELU; emit h as split bf16 (Hhi/Hlo) laid out [node][head*64+d].
__global__ __launch_bounds__(256) void att1_kernel(
    const float* __restrict__ Wh, const float* __restrict__ s1,
    const float* __restrict__ s2, const int* __restrict__ cols,
    const int* __restrict__ cnts, short* __restrict__ Hhi,
    short* __restrict__ Hlo) {
  __shared__ float pj[4][68];
  __shared__ int jj[4][68];
  const int w = threadIdx.x >> 6, lane = threadIdx.x & 63;
  const int pair = blockIdx.x * 4 + w;
  const int h = pair >> 12, i = pair & (N - 1);
  const int cnt = cnts[i];
  const float s1i = s1[(h << 12) + i];
  const float* s2h = s2 + (h << 12);
  float e0 = -1e30f;
  int j0 = 0;
  if (lane < cnt) {
    j0 = cols[i * ELLW + lane];
    float t = s1i + s2h[j0];
    e0 = t > 0.f ? t : ALPHA * t;
  }
  const float m = wred_max(e0);
  float p = (lane < cnt) ? expf(e0 - m) : 0.f;
  const float S = wred_sum(p);
  p *= 1.f / S;                       // lanes >= cnt hold exactly 0
  pj[w][lane] = p;
  jj[w][lane] = (lane < cnt) ? j0 : 0;
  if (lane < 4) { pj[w][64 + lane] = 0.f; jj[w][64 + lane] = 0; }  // overrun pad
  __syncthreads();
  // gather: 4 neighbors in flight; group grp handles neighbor t0+grp,
  // its 16 lanes load a float4 slice of the 64-float Wh row (256 B/group).
  const int grp = lane >> 4, c4 = lane & 15;
  const float* Whh = Wh + (((size_t)h << 12)) * NHID;
  float4 acc = make_float4(0.f, 0.f, 0.f, 0.f);
  for (int t0 = 0; t0 < cnt; t0 += 4) {
    const float pt = pj[w][t0 + grp];
    const int jt = jj[w][t0 + grp];
    const float4 v = *(const float4*)&Whh[(size_t)jt * NHID + c4 * 4];
    acc.x += pt * v.x; acc.y += pt * v.y; acc.z += pt * v.z; acc.w += pt * v.w;
  }
#pragma unroll
  for (int off = 16; off <= 32; off <<= 1) {
    acc.x += __shfl_xor(acc.x, off, 64);
    acc.y += __shfl_xor(acc.y, off, 64);
    acc.z += __shfl_xor(acc.z, off, 64);
    acc.w += __shfl_xor(acc.w, off, 64);
  }
  if (grp == 0) {
    const float o0 = acc.x > 0.f ? acc.x : expf(acc.x) - 1.f;
    const float o1 = acc.y > 0.f ? acc.y : expf(acc.y) - 1.f;
    const float o2 = acc.z > 0.f ? acc.z : expf(acc.z) - 1.f;
    const float o3 = acc.w > 0.f ? acc.w : expf(acc.w) - 1.f;
    short h0, l0, h1, l1, h2, l2, h3, l3;
    split_bf16(o0, h0, l0);
    split_bf16(o1, h1, l1);
    split_bf16(o2, h2, l2);
    split_bf16(o3, h3, l3);
    const size_t base = (size_t)i * 512 + h * 64 + c4 * 4;
    *(short4*)&Hhi[base] = make_short4(h0, h1, h2, h3);
    *(short4*)&Hlo[base] = make_short4(l0, l1, l2, l3);
  }
}

// ---- gemm2: Wh2 = h @ W_out (split-bf16 MFMA, cols padded to 48);
//      fused s1b/s2b = Wh2 . a_out halves.
__global__ __launch_bounds__(256) void gemm2_mfma(
    const short* __restrict__ Hhi, const short* __restrict__ Hlo,
    const short* __restrict__ WOhi, const short* __restrict__ WOlo,
    const float* __restrict__ a_out,
    float* __restrict__ Wh2, float* __restrict__ s1b, float* __restrict__ s2b) {
  __shared__ __align__(16) short Ahi[64 * 72];
  __shared__ __align__(16) short Alo[64 * 72];
  __shared__ __align__(16) short Bhi[NCPAD * 72];
  __shared__ __align__(16) short Blo[NCPAD * 72];
  const int n0 = blockIdx.x * 64;
  const int tid = threadIdx.x;
  const int w = tid >> 6, L = tid & 63;

  floatx4 acc[3];
#pragma unroll
  for (int f = 0; f < 3; f++) acc[f] = (floatx4){0.f, 0.f, 0.f, 0.f};

  for (int k0 = 0; k0 < 512; k0 += 64) {
    __syncthreads();
#pragma unroll
    for (int i = 0; i < 2; i++) {
      const int g = tid + 256 * i;       // 512 A-granules
      const int row = g >> 3, kg = (g & 7) * 8;
      const size_t asrc = (size_t)(n0 + row) * 512 + k0 + kg;
      *(uint4*)&Ahi[row * 72 + kg] = *(const uint4*)&Hhi[asrc];
      *(uint4*)&Alo[row * 72 + kg] = *(const uint4*)&Hlo[asrc];
      if (g < NCPAD * 8) {               // 384 B-granules
        const size_t bsrc = (size_t)row * 512 + k0 + kg;
        *(uint4*)&Bhi[row * 72 + kg] = *(const uint4*)&WOhi[bsrc];
        *(uint4*)&Blo[row * 72 + kg] = *(const uint4*)&WOlo[bsrc];
      }
    }
    __syncthreads();
#pragma unroll
    for (int ks = 0; ks < 2; ks++) {
      const int koff = ks * 32 + (L >> 4) * 8;
      short8 ahi = *(const short8*)&Ahi[(w * 16 + (L & 15)) * 72 + koff];
      short8 alo = *(const short8*)&Alo[(w * 16 + (L & 15)) * 72 + koff];
#pragma unroll
      for (int f = 0; f < 3; f++) {
        short8 bhi = *(const short8*)&Bhi[(f * 16 + (L & 15)) * 72 + koff];
        short8 blo = *(const short8*)&Blo[(f * 16 + (L & 15)) * 72 + koff];
        acc[f] = __builtin_amdgcn_mfma_f32_16x16x32_bf16(ahi, bhi, acc[f], 0, 0, 0);
        acc[f] = __builtin_amdgcn_mfma_f32_16x16x32_bf16(ahi, blo, acc[f], 0, 0, 0);
        acc[f] = __builtin_amdgcn_mfma_f32_16x16x32_bf16(alo, bhi, acc[f], 0, 0, 0);
      }
    }
  }

  const int q = L >> 4, c16 = L & 15;
  float a1v[3], a2v[3];
#pragma unroll
  for (int f = 0; f < 3; f++) {
    const int col = f * 16 + c16;
    a1v[f] = (col < NCLASS) ? a_out[col] : 0.f;
    a2v[f] = (col < NCLASS) ? a_out[NCLASS + col] : 0.f;
  }
  float p1[4] = {0.f, 0.f, 0.f, 0.f}, p2[4] = {0.f, 0.f, 0.f, 0.f};
#pragma unroll
  for (int f = 0; f < 3; f++)
#pragma unroll
    for (int r = 0; r < 4; r++) {
      const float vv = acc[f][r];
      const int col = f * 16 + c16;
      const int row = n0 + w * 16 + q * 4 + r;
      if (col < NCLASS) Wh2[(size_t)row * NCLASS + col] = vv;
      p1[r] += vv * a1v[f];
      p2[r] += vv * a2v[f];
    }
#pragma unroll
  for (int r = 0; r < 4; r++)
#pragma unroll
    for (int o = 1; o < 16; o <<= 1) {
      p1[r] += __shfl_xor(p1[r], o, 64);
      p2[r] += __shfl_xor(p2[r], o, 64);
    }
  if (c16 == 0) {
    const int row = n0 + w * 16 + q * 4;
#pragma unroll
    for (int r = 0; r < 4; r++) {
      s1b[row + r] = p1[r];
      s2b[row + r] = p2[r];
    }
  }
}

// ----------------- layer-2 sparse attention + ELU + log_softmax -> out (fp32)
__global__ __launch_bounds__(256) void att2_kernel(const float* __restrict__ Wh2,
                                                   const float* __restrict__ s1b,
                                                   const float* __restrict__ s2b,
                                                   const int* __restrict__ cols,
                                                   const int* __restrict__ cnts,
                                                   float* __restrict__ out) {
  __shared__ float pj[4][64];
  __shared__ int jj[4][64];
  const int w = threadIdx.x >> 6, lane = threadIdx.x & 63;
  const int i = blockIdx.x * 4 + w;
  const int cnt = cnts[i];
  const float s1i = s1b[i];
  float e0 = -1e30f;
  int j0 = 0;
  if (lane < cnt) {
    j0 = cols[i * ELLW + lane];
    float t = s1i + s2b[j0];
    e0 = t > 0.f ? t : ALPHA * t;
  }
  const float m = wred_max(e0);
  float p = (lane < cnt) ? expf(e0 - m) : 0.f;
  const float S = wred_sum(p);
  p *= 1.f / S;
  pj[w][lane] = p;
  jj[w][lane] = (lane < cnt) ? j0 : 0;
  __syncthreads();
  float acc = 0.f;
  for (int t = 0; t < cnt; t++) {
    const float pt = pj[w][t];
    const int jt = jj[w][t];
    if (lane < NCLASS) acc += pt * Wh2[(size_t)jt * NCLASS + lane];
  }
  const float o = acc > 0.f ? acc : expf(acc) - 1.f;  // ELU
  const float vv = (lane < NCLASS) ? o : -1e30f;
  const float mm = wred_max(vv);
  const float ex = (lane < NCLASS) ? expf(o - mm) : 0.f;
  const float SS = wred_sum(ex);
  if (lane < NCLASS) out[(size_t)i * NCLASS + lane] = o - mm - logf(SS);
}

// ---------------------------------------------------------------------------
extern "C" void kernel_launch(void* const* d_in, const int* in_sizes, int n_in,
                              void* d_out, int out_size, void* d_ws, size_t ws_size,
                              hipStream_t stream) {
  const float* x       = (const float*)d_in[0];   // (4096, 512)
  const float* adj     = (const float*)d_in[1];   // (4096, 4096)
  const float* W_heads = (const float*)d_in[2];   // (8, 512, 64)
  const float* a_heads = (const float*)d_in[3];   // (8, 128, 1)
  const float* W_out   = (const float*)d_in[4];   // (512, 41)
  const float* a_out   = (const float*)d_in[5];   // (82, 1)
  float* out = (float*)d_out;                     // (4096, 41)

  // workspace layout (~29 MB)
  float* ws   = (float*)d_ws;
  float* Wh   = ws;                                  // 8*4096*64
  float* s1   = Wh + (size_t)NHEADS * N * NHID;      // 8*4096
  float* s2   = s1 + NHEADS * N;                     // 8*4096
  float* Wh2  = s2 + NHEADS * N;                     // 4096*41
  float* s1b  = Wh2 + (size_t)N * NCLASS;            // 4096
  float* s2b  = s1b + N;                             // 4096
  int* cnts   = (int*)(s2b + N);                     // 4096
  int* cols   = cnts + N;                            // 4096*64
  short* Xhi  = (short*)(cols + N * ELLW);           // 4096*512
  short* Xlo  = Xhi + (size_t)N * NFEAT;             // 4096*512
  short* Wthi = Xlo + (size_t)N * NFEAT;             // 8*64*512
  short* Wtlo = Wthi + (size_t)NHEADS * NHID * NFEAT;// 8*64*512
  short* WOhi = Wtlo + (size_t)NHEADS * NHID * NFEAT;// 48*512
  short* WOlo = WOhi + (size_t)NCPAD * 512;          // 48*512
  short* Hhi  = WOlo + (size_t)NCPAD * 512;          // 4096*512
  short* Hlo  = Hhi + (size_t)N * NFEAT;             // 4096*512

  hipLaunchKernelGGL(setup, dim3(7264), dim3(256), 0, stream,
                     x, W_heads, W_out, adj, Xhi, Xlo, Wthi, Wtlo, WOhi, WOlo, cols, cnts);
  hipLaunchKernelGGL(wh_gemm_mfma, dim3(NHEADS, N / 64), dim3(256), 0, stream,
                     Xhi, Xlo, Wthi, Wtlo, a_heads, Wh, s1, s2);
  hipLaunchKernelGGL(att1_kernel, dim3(NHEADS * N / 4), dim3(256), 0, stream,
                     Wh, s1, s2, cols, cnts, Hhi, Hlo);
  hipLaunchKernelGGL(gemm2_mfma, dim3(N / 64), dim3(256), 0, stream,
                     Hhi, Hlo, WOhi, WOlo, a_out, Wh2, s1b, s2b);
  hipLaunchKernelGGL(att2_kernel, dim3(N / 4), dim3(256), 0, stream,
                     Wh2, s1b, s2b, cols, cnts, out);
}

// Round 7
// 168.717 us; speedup vs baseline: 1.1572x; 1.0089x over previous
//
#include <hip/hip_runtime.h>
#include <hip/hip_bf16.h>
#include <math.h>

// GAT, N=4096, NFEAT=512, NHID=64, NHEADS=8, NCLASS=41, EDGE_P=0.004.
// Adjacency ~17 nnz/row -> both attention layers are exactly sparse.
// gemm1 (x@W_heads) and gemm2 (h@W_out) use bf16 MFMA with split-bf16 (hi+lo)
// 3-term products for fp32-grade accuracy. att1 gathers 4 neighbors/iter with
// float4 loads and emits h pre-split to bf16 for gemm2.
// setup = build_ell + all input splitting/transposition fused in one launch.
// gemm1 grid is XCD-swizzled: id = (t&7) + 8h + 64(t>>3) puts all 8 heads of a
// row-tile on one XCD (A-tile reused 8x from L2; B set 1 MB stays resident).

#define N 4096
#define NFEAT 512
#define NHID 64
#define NHEADS 8
#define NCLASS 41
#define NCPAD 48
#define ALPHA 0.2f
#define ELLW 64   // Binomial(4096,0.004): mean 16.4, P(cnt>64) ~ 1e-18

using short8  = __attribute__((ext_vector_type(8))) short;
using floatx4 = __attribute__((ext_vector_type(4))) float;

__device__ __forceinline__ float wred_max(float v) {
#pragma unroll
  for (int o = 32; o; o >>= 1) v = fmaxf(v, __shfl_xor(v, o, 64));
  return v;
}
__device__ __forceinline__ float wred_sum(float v) {
#pragma unroll
  for (int o = 32; o; o >>= 1) v += __shfl_xor(v, o, 64);
  return v;
}

__device__ __forceinline__ void split_bf16(float v, short& hi, short& lo) {
  __hip_bfloat16 hb = __float2bfloat16(v);
  float hf = __bfloat162float(hb);
  __hip_bfloat16 lb = __float2bfloat16(v - hf);
  hi = *reinterpret_cast<short*>(&hb);
  lo = *reinterpret_cast<short*>(&lb);
}

// ---- setup: fused prep (x split, W_heads split+T, W_out split+T) + build_ell
// blocks [0,2048): x. [2048,3072): W_heads. [3072,3168): W_out. [3168,7264): adj.
__global__ __launch_bounds__(256) void setup(const float* __restrict__ x,
                                             const float* __restrict__ W,
                                             const float* __restrict__ W_out,
                                             const float* __restrict__ adj,
                                             short* __restrict__ Xhi,
                                             short* __restrict__ Xlo,
                                             short* __restrict__ Wthi,
                                             short* __restrict__ Wtlo,
                                             short* __restrict__ WOhi,
                                             short* __restrict__ WOlo,
                                             int* __restrict__ cols,
                                             int* __restrict__ cnts) {
  if (blockIdx.x >= 3168) {
    // -------- build ELL neighbor lists
    __shared__ int c;
    const int row = blockIdx.x - 3168;
    if (threadIdx.x == 0) c = 0;
    __syncthreads();
    const float4* arow = (const float4*)(adj + (size_t)row * N);
    for (int j4 = threadIdx.x; j4 < N / 4; j4 += 256) {
      float4 v = arow[j4];
      if (v.x > 0.f) { int p = atomicAdd(&c, 1); if (p < ELLW) cols[row * ELLW + p] = j4 * 4 + 0; }
      if (v.y > 0.f) { int p = atomicAdd(&c, 1); if (p < ELLW) cols[row * ELLW + p] = j4 * 4 + 1; }
      if (v.z > 0.f) { int p = atomicAdd(&c, 1); if (p < ELLW) cols[row * ELLW + p] = j4 * 4 + 2; }
      if (v.w > 0.f) { int p = atomicAdd(&c, 1); if (p < ELLW) cols[row * ELLW + p] = j4 * 4 + 3; }
    }
    __syncthreads();
    if (threadIdx.x == 0) cnts[row] = min(c, ELLW);
  } else if (blockIdx.x < 2048) {
    const int t = blockIdx.x * 256 + threadIdx.x;      // float4 index
    const float4 v = ((const float4*)x)[t];
    short h0, l0, h1, l1, h2, l2, h3, l3;
    split_bf16(v.x, h0, l0);
    split_bf16(v.y, h1, l1);
    split_bf16(v.z, h2, l2);
    split_bf16(v.w, h3, l3);
    ((short4*)Xhi)[t] = make_short4(h0, h1, h2, h3);
    ((short4*)Xlo)[t] = make_short4(l0, l1, l2, l3);
  } else if (blockIdx.x < 3072) {
    const int t = (blockIdx.x - 2048) * 256 + threadIdx.x;  // 0..262143
    const int h = t >> 15, r = t & 32767;
    const int d = r >> 9, k = r & 511;                 // write-coalesced
    float v = W[(size_t)h * 32768 + (size_t)k * 64 + d];
    short hi, lo;
    split_bf16(v, hi, lo);
    Wthi[(size_t)h * 32768 + d * 512 + k] = hi;
    Wtlo[(size_t)h * 32768 + d * 512 + k] = lo;
  } else {
    const int t = (blockIdx.x - 3072) * 256 + threadIdx.x;  // 0..24575
    const int c = t >> 9, k = t & 511;
    float v = (c < NCLASS) ? W_out[(size_t)k * NCLASS + c] : 0.f;
    short hi, lo;
    split_bf16(v, hi, lo);
    WOhi[c * 512 + k] = hi;
    WOlo[c * 512 + k] = lo;
  }
}

// ----------------- Wh = x @ W_heads via split-bf16 MFMA; fused s1/s2 epilogue
// 1D grid of 512, XCD-swizzled: id = (t&7) + 8*h + 64*(t>>3).
__global__ __launch_bounds__(256) void wh_gemm_mfma(
    const short* __restrict__ Xhi, const short* __restrict__ Xlo,
    const short* __restrict__ Wthi, const short* __restrict__ Wtlo,
    const float* __restrict__ a_heads,
    float* __restrict__ Wh, float* __restrict__ s1, float* __restrict__ s2) {
  __shared__ __align__(16) short Ahi[64 * 72];
  __shared__ __align__(16) short Alo[64 * 72];
  __shared__ __align__(16) short Bhi[64 * 72];
  __shared__ __align__(16) short Blo[64 * 72];
  const int id = blockIdx.x;
  const int h = (id >> 3) & 7;
  const int tile = (id & 7) + ((id >> 6) << 3);
  const int n0 = tile * 64;
  const int tid = threadIdx.x;
  const int w = tid >> 6, L = tid & 63;

  floatx4 acc[4];
#pragma unroll
  for (int f = 0; f < 4; f++) acc[f] = (floatx4){0.f, 0.f, 0.f, 0.f};

  for (int k0 = 0; k0 < NFEAT; k0 += 64) {
    __syncthreads();
#pragma unroll
    for (int i = 0; i < 2; i++) {
      const int g = tid + 256 * i;       // (row, 8-elem k group)
      const int row = g >> 3, kg = (g & 7) * 8;
      const size_t asrc = (size_t)(n0 + row) * NFEAT + k0 + kg;
      *(uint4*)&Ahi[row * 72 + kg] = *(const uint4*)&Xhi[asrc];
      *(uint4*)&Alo[row * 72 + kg] = *(const uint4*)&Xlo[asrc];
      const size_t bsrc = (size_t)h * 32768 + (size_t)row * 512 + k0 + kg;
      *(uint4*)&Bhi[row * 72 + kg] = *(const uint4*)&Wthi[bsrc];
      *(uint4*)&Blo[row * 72 + kg] = *(const uint4*)&Wtlo[bsrc];
    }
    __syncthreads();
#pragma unroll
    for (int ks = 0; ks < 2; ks++) {
      const int koff = ks * 32 + (L >> 4) * 8;
      short8 ahi = *(const short8*)&Ahi[(w * 16 + (L & 15)) * 72 + koff];
      short8 alo = *(const short8*)&Alo[(w * 16 + (L & 15)) * 72 + koff];
#pragma unroll
      for (int f = 0; f < 4; f++) {
        short8 bhi = *(const short8*)&Bhi[(f * 16 + (L & 15)) * 72 + koff];
        short8 blo = *(const short8*)&Blo[(f * 16 + (L & 15)) * 72 + koff];
        acc[f] = __builtin_amdgcn_mfma_f32_16x16x32_bf16(ahi, bhi, acc[f], 0, 0, 0);
        acc[f] = __builtin_amdgcn_mfma_f32_16x16x32_bf16(ahi, blo, acc[f], 0, 0, 0);
        acc[f] = __builtin_amdgcn_mfma_f32_16x16x32_bf16(alo, bhi, acc[f], 0, 0, 0);
      }
    }
  }

  const int q = L >> 4, c16 = L & 15;
  float a1v[4], a2v[4];
#pragma unroll
  for (int f = 0; f < 4; f++) {
    a1v[f] = a_heads[h * 128 + f * 16 + c16];
    a2v[f] = a_heads[h * 128 + 64 + f * 16 + c16];
  }
  float p1[4] = {0.f, 0.f, 0.f, 0.f}, p2[4] = {0.f, 0.f, 0.f, 0.f};
#pragma unroll
  for (int f = 0; f < 4; f++)
#pragma unroll
    for (int r = 0; r < 4; r++) {
      const float vv = acc[f][r];
      const int row = n0 + w * 16 + q * 4 + r;
      Wh[((size_t)(h << 12) + row) * NHID + f * 16 + c16] = vv;
      p1[r] += vv * a1v[f];
      p2[r] += vv * a2v[f];
    }
#pragma unroll
  for (int r = 0; r < 4; r++)
#pragma unroll
    for (int o = 1; o < 16; o <<= 1) {
      p1[r] += __shfl_xor(p1[r], o, 64);
      p2[r] += __shfl_xor(p2[r], o, 64);
    }
  if (c16 == 0) {
    const int row = n0 + w * 16 + q * 4;
#pragma unroll
    for (int r = 0; r < 4; r++) {
      s1[(h << 12) + row + r] = p1[r];
      s2[(h << 12) + row + r] = p2[r];
    }
  }
}

// ---- layer-1 attention: wave per (i,h); 4-neighbor-parallel float4 gather;
//      ELU; emit h as split bf16 (Hhi/Hlo) laid out [node][head*64+d].
__global__ __launch_bounds__(256) void att1_kernel(
    const float* __restrict__ Wh, const float* __restrict__ s1,
    const float* __restrict__ s2, const int* __restrict__ cols,
    const int* __restrict__ cnts, short* __restrict__ Hhi,
    short* __restrict__ Hlo) {
  __shared__ float pj[4][68];
  __shared__ int jj[4][68];
  const int w = threadIdx.x >> 6, lane = threadIdx.x & 63;
  const int pair = blockIdx.x * 4 + w;
  const int h = pair >> 12, i = pair & (N - 1);
  const int cnt = cnts[i];
  const float s1i = s1[(h << 12) + i];
  const float* s2h = s2 + (h << 12);
  float e0 = -1e30f;
  int j0 = 0;
  if (lane < cnt) {
    j0 = cols[i * ELLW + lane];
    float t = s1i + s2h[j0];
    e0 = t > 0.f ? t : ALPHA * t;
  }
  const float m = wred_max(e0);
  float p = (lane < cnt) ? expf(e0 - m) : 0.f;
  const float S = wred_sum(p);
  p *= 1.f / S;                       // lanes >= cnt hold exactly 0
  pj[w][lane] = p;
  jj[w][lane] = (lane < cnt) ? j0 : 0;
  if (lane < 4) { pj[w][64 + lane] = 0.f; jj[w][64 + lane] = 0; }  // overrun pad
  __syncthreads();
  // gather: 4 neighbors in flight; group grp handles neighbor t0+grp,
  // its 16 lanes load a float4 slice of the 64-float Wh row (256 B/group).
  const int grp = lane >> 4, c4 = lane & 15;
  const float* Whh = Wh + (((size_t)h << 12)) * NHID;
  float4 acc = make_float4(0.f, 0.f, 0.f, 0.f);
  for (int t0 = 0; t0 < cnt; t0 += 4) {
    const float pt = pj[w][t0 + grp];
    const int jt = jj[w][t0 + grp];
    const float4 v = *(const float4*)&Whh[(size_t)jt * NHID + c4 * 4];
    acc.x += pt * v.x; acc.y += pt * v.y; acc.z += pt * v.z; acc.w += pt * v.w;
  }
#pragma unroll
  for (int off = 16; off <= 32; off <<= 1) {
    acc.x += __shfl_xor(acc.x, off, 64);
    acc.y += __shfl_xor(acc.y, off, 64);
    acc.z += __shfl_xor(acc.z, off, 64);
    acc.w += __shfl_xor(acc.w, off, 64);
  }
  if (grp == 0) {
    const float o0 = acc.x > 0.f ? acc.x : expf(acc.x) - 1.f;
    const float o1 = acc.y > 0.f ? acc.y : expf(acc.y) - 1.f;
    const float o2 = acc.z > 0.f ? acc.z : expf(acc.z) - 1.f;
    const float o3 = acc.w > 0.f ? acc.w : expf(acc.w) - 1.f;
    short h0, l0, h1, l1, h2, l2, h3, l3;
    split_bf16(o0, h0, l0);
    split_bf16(o1, h1, l1);
    split_bf16(o2, h2, l2);
    split_bf16(o3, h3, l3);
    const size_t base = (size_t)i * 512 + h * 64 + c4 * 4;
    *(short4*)&Hhi[base] = make_short4(h0, h1, h2, h3);
    *(short4*)&Hlo[base] = make_short4(l0, l1, l2, l3);
  }
}

// ---- gemm2: Wh2 = h @ W_out (split-bf16 MFMA, cols padded to 48);
//      fused s1b/s2b = Wh2 . a_out halves.
__global__ __launch_bounds__(256) void gemm2_mfma(
    const short* __restrict__ Hhi, const short* __restrict__ Hlo,
    const short* __restrict__ WOhi, const short* __restrict__ WOlo,
    const float* __restrict__ a_out,
    float* __restrict__ Wh2, float* __restrict__ s1b, float* __restrict__ s2b) {
  __shared__ __align__(16) short Ahi[64 * 72];
  __shared__ __align__(16) short Alo[64 * 72];
  __shared__ __align__(16) short Bhi[NCPAD * 72];
  __shared__ __align__(16) short Blo[NCPAD * 72];
  const int n0 = blockIdx.x * 64;
  const int tid = threadIdx.x;
  const int w = tid >> 6, L = tid & 63;

  floatx4 acc[3];
#pragma unroll
  for (int f = 0; f < 3; f++) acc[f] = (floatx4){0.f, 0.f, 0.f, 0.f};

  for (int k0 = 0; k0 < 512; k0 += 64) {
    __syncthreads();
#pragma unroll
    for (int i = 0; i < 2; i++) {
      const int g = tid + 256 * i;       // 512 A-granules
      const int row = g >> 3, kg = (g & 7) * 8;
      const size_t asrc = (size_t)(n0 + row) * 512 + k0 + kg;
      *(uint4*)&Ahi[row * 72 + kg] = *(const uint4*)&Hhi[asrc];
      *(uint4*)&Alo[row * 72 + kg] = *(const uint4*)&Hlo[asrc];
      if (g < NCPAD * 8) {               // 384 B-granules
        const size_t bsrc = (size_t)row * 512 + k0 + kg;
        *(uint4*)&Bhi[row * 72 + kg] = *(const uint4*)&WOhi[bsrc];
        *(uint4*)&Blo[row * 72 + kg] = *(const uint4*)&WOlo[bsrc];
      }
    }
    __syncthreads();
#pragma unroll
    for (int ks = 0; ks < 2; ks++) {
      const int koff = ks * 32 + (L >> 4) * 8;
      short8 ahi = *(const short8*)&Ahi[(w * 16 + (L & 15)) * 72 + koff];
      short8 alo = *(const short8*)&Alo[(w * 16 + (L & 15)) * 72 + koff];
#pragma unroll
      for (int f = 0; f < 3; f++) {
        short8 bhi = *(const short8*)&Bhi[(f * 16 + (L & 15)) * 72 + koff];
        short8 blo = *(const short8*)&Blo[(f * 16 + (L & 15)) * 72 + koff];
        acc[f] = __builtin_amdgcn_mfma_f32_16x16x32_bf16(ahi, bhi, acc[f], 0, 0, 0);
        acc[f] = __builtin_amdgcn_mfma_f32_16x16x32_bf16(ahi, blo, acc[f], 0, 0, 0);
        acc[f] = __builtin_amdgcn_mfma_f32_16x16x32_bf16(alo, bhi, acc[f], 0, 0, 0);
      }
    }
  }

  const int q = L >> 4, c16 = L & 15;
  float a1v[3], a2v[3];
#pragma unroll
  for (int f = 0; f < 3; f++) {
    const int col = f * 16 + c16;
    a1v[f] = (col < NCLASS) ? a_out[col] : 0.f;
    a2v[f] = (col < NCLASS) ? a_out[NCLASS + col] : 0.f;
  }
  float p1[4] = {0.f, 0.f, 0.f, 0.f}, p2[4] = {0.f, 0.f, 0.f, 0.f};
#pragma unroll
  for (int f = 0; f < 3; f++)
#pragma unroll
    for (int r = 0; r < 4; r++) {
      const float vv = acc[f][r];
      const int col = f * 16 + c16;
      const int row = n0 + w * 16 + q * 4 + r;
      if (col < NCLASS) Wh2[(size_t)row * NCLASS + col] = vv;
      p1[r] += vv * a1v[f];
      p2[r] += vv * a2v[f];
    }
#pragma unroll
  for (int r = 0; r < 4; r++)
#pragma unroll
    for (int o = 1; o < 16; o <<= 1) {
      p1[r] += __shfl_xor(p1[r], o, 64);
      p2[r] += __shfl_xor(p2[r], o, 64);
    }
  if (c16 == 0) {
    const int row = n0 + w * 16 + q * 4;
#pragma unroll
    for (int r = 0; r < 4; r++) {
      s1b[row + r] = p1[r];
      s2b[row + r] = p2[r];
    }
  }
}

// ----------------- layer-2 sparse attention + ELU + log_softmax -> out (fp32)
__global__ __launch_bounds__(256) void att2_kernel(const float* __restrict__ Wh2,
                                                   const float* __restrict__ s1b,
                                                   const float* __restrict__ s2b,
                                                   const int* __restrict__ cols,
                                                   const int* __restrict__ cnts,
                                                   float* __restrict__ out) {
  __shared__ float pj[4][64];
  __shared__ int jj[4][64];
  const int w = threadIdx.x >> 6, lane = threadIdx.x & 63;
  const int i = blockIdx.x * 4 + w;
  const int cnt = cnts[i];
  const float s1i = s1b[i];
  float e0 = -1e30f;
  int j0 = 0;
  if (lane < cnt) {
    j0 = cols[i * ELLW + lane];
    float t = s1i + s2b[j0];
    e0 = t > 0.f ? t : ALPHA * t;
  }
  const float m = wred_max(e0);
  float p = (lane < cnt) ? expf(e0 - m) : 0.f;
  const float S = wred_sum(p);
  p *= 1.f / S;
  pj[w][lane] = p;
  jj[w][lane] = (lane < cnt) ? j0 : 0;
  __syncthreads();
  float acc = 0.f;
  for (int t = 0; t < cnt; t++) {
    const float pt = pj[w][t];
    const int jt = jj[w][t];
    if (lane < NCLASS) acc += pt * Wh2[(size_t)jt * NCLASS + lane];
  }
  const float o = acc > 0.f ? acc : expf(acc) - 1.f;  // ELU
  const float vv = (lane < NCLASS) ? o : -1e30f;
  const float mm = wred_max(vv);
  const float ex = (lane < NCLASS) ? expf(o - mm) : 0.f;
  const float SS = wred_sum(ex);
  if (lane < NCLASS) out[(size_t)i * NCLASS + lane] = o - mm - logf(SS);
}

// ---------------------------------------------------------------------------
extern "C" void kernel_launch(void* const* d_in, const int* in_sizes, int n_in,
                              void* d_out, int out_size, void* d_ws, size_t ws_size,
                              hipStream_t stream) {
  const float* x       = (const float*)d_in[0];   // (4096, 512)
  const float* adj     = (const float*)d_in[1];   // (4096, 4096)
  const float* W_heads = (const float*)d_in[2];   // (8, 512, 64)
  const float* a_heads = (const float*)d_in[3];   // (8, 128, 1)
  const float* W_out   = (const float*)d_in[4];   // (512, 41)
  const float* a_out   = (const float*)d_in[5];   // (82, 1)
  float* out = (float*)d_out;                     // (4096, 41)

  // workspace layout (~29 MB)
  float* ws   = (float*)d_ws;
  float* Wh   = ws;                                  // 8*4096*64
  float* s1   = Wh + (size_t)NHEADS * N * NHID;      // 8*4096
  float* s2   = s1 + NHEADS * N;                     // 8*4096
  float* Wh2  = s2 + NHEADS * N;                     // 4096*41
  float* s1b  = Wh2 + (size_t)N * NCLASS;            // 4096
  float* s2b  = s1b + N;                             // 4096
  int* cnts   = (int*)(s2b + N);                     // 4096
  int* cols   = cnts + N;                            // 4096*64
  short* Xhi  = (short*)(cols + N * ELLW);           // 4096*512
  short* Xlo  = Xhi + (size_t)N * NFEAT;             // 4096*512
  short* Wthi = Xlo + (size_t)N * NFEAT;             // 8*64*512
  short* Wtlo = Wthi + (size_t)NHEADS * NHID * NFEAT;// 8*64*512
  short* WOhi = Wtlo + (size_t)NHEADS * NHID * NFEAT;// 48*512
  short* WOlo = WOhi + (size_t)NCPAD * 512;          // 48*512
  short* Hhi  = WOlo + (size_t)NCPAD * 512;          // 4096*512
  short* Hlo  = Hhi + (size_t)N * NFEAT;             // 4096*512

  hipLaunchKernelGGL(setup, dim3(7264), dim3(256), 0, stream,
                     x, W_heads, W_out, adj, Xhi, Xlo, Wthi, Wtlo, WOhi, WOlo, cols, cnts);
  hipLaunchKernelGGL(wh_gemm_mfma, dim3(NHEADS * N / 64), dim3(256), 0, stream,
                     Xhi, Xlo, Wthi, Wtlo, a_heads, Wh, s1, s2);
  hipLaunchKernelGGL(att1_kernel, dim3(NHEADS * N / 4), dim3(256), 0, stream,
                     Wh, s1, s2, cols, cnts, Hhi, Hlo);
  hipLaunchKernelGGL(gemm2_mfma, dim3(N / 64), dim3(256), 0, stream,
                     Hhi, Hlo, WOhi, WOlo, a_out, Wh2, s1b, s2b);
  hipLaunchKernelGGL(att2_kernel, dim3(N / 4), dim3(256), 0, stream,
                     Wh2, s1b, s2b, cols, cnts, out);
}